// Round 1
// baseline (862.356 us; speedup 1.0000x reference)
//
#include <hip/hip_runtime.h>
#include <math.h>

#define N_NODES 50000
#define N_EDGES 800000
#define N_GRAPHS 512
#define D 64
#define DE 32

// ---------------------------------------------------------------------------
// T table layout per node n (256 floats):
//   T[n*256 +   0 + j] = Af[n][j] = x[n] @ Wf[0:64]  + bf[j]   (dst part, f)
//   T[n*256 +  64 + j] = As[n][j] = x[n] @ Ws[0:64]  + bs[j]   (dst part, s)
//   T[n*256 + 128 + j] = Bf[n][j] = x[n] @ Wf[64:128]          (src part, f)
//   T[n*256 + 192 + j] = Bs[n][j] = x[n] @ Ws[64:128]          (src part, s)
// ---------------------------------------------------------------------------

__global__ __launch_bounds__(256) void node_transform(
    const float* __restrict__ H,          // [N_NODES][64]
    const float* __restrict__ Wf,         // [160][64]
    const float* __restrict__ Ws,         // [160][64]
    const float* __restrict__ bf,         // [64]
    const float* __restrict__ bs,         // [64]
    float* __restrict__ T)                // [N_NODES][256]
{
    const int lane = threadIdx.x & 63;
    const int tbl  = (threadIdx.x >> 6) & 3;  // 0:Af 1:As 2:Bf 3:Bs

    const float* W = (tbl == 0 || tbl == 2) ? Wf : Ws;
    const int roff = (tbl < 2) ? 0 : 64;

    // weight column for this (tbl, lane): 64 VGPRs
    float wcol[64];
#pragma unroll
    for (int c = 0; c < 64; ++c) wcol[c] = W[(roff + c) * 64 + lane];

    float bias = 0.0f;
    if (tbl == 0) bias = bf[lane];
    else if (tbl == 1) bias = bs[lane];

    for (int n = blockIdx.x; n < N_NODES; n += gridDim.x) {
        const float4* xr = (const float4*)(H + (size_t)n * D);
        float acc = bias;
#pragma unroll
        for (int c4 = 0; c4 < 16; ++c4) {
            float4 v = xr[c4];
            acc = fmaf(v.x, wcol[4 * c4 + 0], acc);
            acc = fmaf(v.y, wcol[4 * c4 + 1], acc);
            acc = fmaf(v.z, wcol[4 * c4 + 2], acc);
            acc = fmaf(v.w, wcol[4 * c4 + 3], acc);
        }
        T[(size_t)n * 256 + tbl * 64 + lane] = acc;
    }
}

// One wave per edge (grid-strided). Lane j computes output channel j.
__global__ __launch_bounds__(256) void edge_message(
    const float* __restrict__ T,          // [N_NODES][256]
    const int* __restrict__ ei,           // [2][N_EDGES]
    const float* __restrict__ ea,         // [N_EDGES][32]
    const float* __restrict__ Wf,         // [160][64] (rows 128..159 used)
    const float* __restrict__ Ws,
    float* __restrict__ hout)             // [N_NODES][64], pre-init to input h
{
    const int lane = threadIdx.x & 63;
    const int wid  = threadIdx.x >> 6;

    // edge-attr weight columns in registers: 64 VGPRs
    float wfe[DE], wse[DE];
#pragma unroll
    for (int c = 0; c < DE; ++c) {
        wfe[c] = Wf[(128 + c) * 64 + lane];
        wse[c] = Ws[(128 + c) * 64 + lane];
    }

    const int nwaves = gridDim.x * 4;
    for (int e0 = blockIdx.x * 4 + wid; e0 < N_EDGES; e0 += nwaves) {
        const int e   = __builtin_amdgcn_readfirstlane(e0);
        const int src = ei[e];
        const int dst = ei[N_EDGES + e];

        const float* td = T + (size_t)dst * 256;
        const float* ts = T + (size_t)src * 256;
        float accf = td[lane]      + ts[128 + lane];   // Af[dst]+bf + Bf[src]
        float accs = td[64 + lane] + ts[192 + lane];   // As[dst]+bs + Bs[src]

        float eav = ea[(size_t)e * DE + (lane & (DE - 1))];
#pragma unroll
        for (int c = 0; c < DE; ++c) {
            float z = __shfl(eav, c);
            accf = fmaf(z, wfe[c], accf);
            accs = fmaf(z, wse[c], accs);
        }

        // sigmoid(accf) * softplus(accs), numerically stable
        float sig = 1.0f / (1.0f + __expf(-accf));
        float sp  = fmaxf(accs, 0.0f) + log1pf(__expf(-fabsf(accs)));
        atomicAdd(&hout[(size_t)dst * D + lane], sig * sp);
    }
}

// segment_sum(h, batch) into pooled[N_GRAPHS][64]
__global__ __launch_bounds__(256) void pool_kernel(
    const float* __restrict__ h,          // [N_NODES][64]
    const int* __restrict__ batch,        // [N_NODES]
    float* __restrict__ pooled)           // [N_GRAPHS][64], pre-zeroed
{
    const int lane = threadIdx.x & 63;
    const int wid  = threadIdx.x >> 6;
    const int nwaves = gridDim.x * 4;
    for (int n = blockIdx.x * 4 + wid; n < N_NODES; n += nwaves) {
        const int g = batch[n];
        atomicAdd(&pooled[(size_t)g * D + lane], h[(size_t)n * D + lane]);
    }
}

__global__ __launch_bounds__(256) void out_kernel(
    const float* __restrict__ pooled,     // [N_GRAPHS][64]
    const float* __restrict__ Wout,       // [64]
    const float* __restrict__ bout,       // [1]
    float* __restrict__ out)              // [N_GRAPHS]
{
    const int g = blockIdx.x * blockDim.x + threadIdx.x;
    if (g >= N_GRAPHS) return;
    float acc = bout[0];
#pragma unroll
    for (int j = 0; j < D; ++j) acc = fmaf(pooled[(size_t)g * D + j], Wout[j], acc);
    out[g] = acc;
}

extern "C" void kernel_launch(void* const* d_in, const int* in_sizes, int n_in,
                              void* d_out, int out_size, void* d_ws, size_t ws_size,
                              hipStream_t stream) {
    const float* x     = (const float*)d_in[0];
    const int*   ei    = (const int*)  d_in[1];
    const float* ea    = (const float*)d_in[2];
    const int*   batch = (const int*)  d_in[3];
    const float* Wf1   = (const float*)d_in[4];
    const float* bf1   = (const float*)d_in[5];
    const float* Ws1   = (const float*)d_in[6];
    const float* bs1   = (const float*)d_in[7];
    const float* Wf2   = (const float*)d_in[8];
    const float* bf2   = (const float*)d_in[9];
    const float* Ws2   = (const float*)d_in[10];
    const float* bs2   = (const float*)d_in[11];
    const float* Wout  = (const float*)d_in[12];
    const float* bout  = (const float*)d_in[13];
    float* out = (float*)d_out;

    // workspace layout
    float* T      = (float*)d_ws;                       // 50000*256
    float* h1     = T + (size_t)N_NODES * 256;          // 50000*64
    float* h2     = h1 + (size_t)N_NODES * D;           // 50000*64
    float* pooled = h2 + (size_t)N_NODES * D;           // 512*64

    const int GRID_N = 1024;    // node_transform blocks
    const int GRID_E = 25000;   // edge_message blocks (4 waves each, 8 edges/wave)

    // ---- layer 1 ----
    node_transform<<<GRID_N, 256, 0, stream>>>(x, Wf1, Ws1, bf1, bs1, T);
    hipMemcpyAsync(h1, x, (size_t)N_NODES * D * sizeof(float),
                   hipMemcpyDeviceToDevice, stream);
    edge_message<<<GRID_E, 256, 0, stream>>>(T, ei, ea, Wf1, Ws1, h1);

    // ---- layer 2 ----
    node_transform<<<GRID_N, 256, 0, stream>>>(h1, Wf2, Ws2, bf2, bs2, T);
    hipMemcpyAsync(h2, h1, (size_t)N_NODES * D * sizeof(float),
                   hipMemcpyDeviceToDevice, stream);
    edge_message<<<GRID_E, 256, 0, stream>>>(T, ei, ea, Wf2, Ws2, h2);

    // ---- pool + out ----
    hipMemsetAsync(pooled, 0, (size_t)N_GRAPHS * D * sizeof(float), stream);
    pool_kernel<<<12500, 256, 0, stream>>>(h2, batch, pooled);
    out_kernel<<<2, 256, 0, stream>>>(pooled, Wout, bout, out);
}

// Round 2
// 855.913 us; speedup vs baseline: 1.0075x; 1.0075x over previous
//
#include <hip/hip_runtime.h>
#include <math.h>

#define N_NODES 50000
#define N_EDGES 800000
#define N_GRAPHS 512
#define D 64
#define DE 32

// ---------------------------------------------------------------------------
// T table layout per node n (256 floats):
//   T[n*256 +   0 + j] = Af[n][j] = x[n] @ Wf[0:64]  + bf[j]   (dst part, f)
//   T[n*256 +  64 + j] = As[n][j] = x[n] @ Ws[0:64]  + bs[j]   (dst part, s)
//   T[n*256 + 128 + j] = Bf[n][j] = x[n] @ Wf[64:128]          (src part, f)
//   T[n*256 + 192 + j] = Bs[n][j] = x[n] @ Ws[64:128]          (src part, s)
// ---------------------------------------------------------------------------

// (256,4): cap VGPR budget at 128 so the 64-element wcol array registerizes
// instead of being re-loaded from L1 every node (R1 lesson: default heuristic
// allocated only 48 VGPRs and sank the weight loads into the loop).
__global__ __launch_bounds__(256, 4) void node_transform(
    const float* __restrict__ H,          // [N_NODES][64]
    const float* __restrict__ Wf,         // [160][64]
    const float* __restrict__ Ws,         // [160][64]
    const float* __restrict__ bf,         // [64]
    const float* __restrict__ bs,         // [64]
    float* __restrict__ T)                // [N_NODES][256]
{
    const int lane = threadIdx.x & 63;
    const int tbl  = (threadIdx.x >> 6) & 3;  // 0:Af 1:As 2:Bf 3:Bs

    const float* W = (tbl == 0 || tbl == 2) ? Wf : Ws;
    const int roff = (tbl < 2) ? 0 : 64;

    // weight column for this (tbl, lane): 64 VGPRs
    float wcol[64];
#pragma unroll
    for (int c = 0; c < 64; ++c) wcol[c] = W[(roff + c) * 64 + lane];

    float bias = 0.0f;
    if (tbl == 0) bias = bf[lane];
    else if (tbl == 1) bias = bs[lane];

    for (int n = blockIdx.x; n < N_NODES; n += gridDim.x) {
        const float4* xr = (const float4*)(H + (size_t)n * D);
        float acc = bias;
#pragma unroll
        for (int c4 = 0; c4 < 16; ++c4) {
            float4 v = xr[c4];
            acc = fmaf(v.x, wcol[4 * c4 + 0], acc);
            acc = fmaf(v.y, wcol[4 * c4 + 1], acc);
            acc = fmaf(v.z, wcol[4 * c4 + 2], acc);
            acc = fmaf(v.w, wcol[4 * c4 + 3], acc);
        }
        T[(size_t)n * 256 + tbl * 64 + lane] = acc;
    }
}

// One wave per edge (grid-strided). Lane j computes output channel j.
// (256,4): 128-VGPR budget — wfe[32]+wse[32] MUST live in VGPRs (R1: default
// alloc was 48 VGPRs -> 64 weight reloads/edge from L1 = 16KB/edge = the
// entire 351us). ~85 live VGPRs fits; 4 waves/EU = 16 waves/CU occupancy.
__global__ __launch_bounds__(256, 4) void edge_message(
    const float* __restrict__ T,          // [N_NODES][256]
    const int* __restrict__ ei,           // [2][N_EDGES]
    const float* __restrict__ ea,         // [N_EDGES][32]
    const float* __restrict__ Wf,         // [160][64] (rows 128..159 used)
    const float* __restrict__ Ws,
    float* __restrict__ hout)             // [N_NODES][64], pre-init to input h
{
    const int lane = threadIdx.x & 63;
    const int wid  = threadIdx.x >> 6;

    // edge-attr weight columns in registers: 64 VGPRs
    float wfe[DE], wse[DE];
#pragma unroll
    for (int c = 0; c < DE; ++c) {
        wfe[c] = Wf[(128 + c) * 64 + lane];
        wse[c] = Ws[(128 + c) * 64 + lane];
    }

    const int nwaves = gridDim.x * 4;
    for (int e0 = blockIdx.x * 4 + wid; e0 < N_EDGES; e0 += nwaves) {
        const int e   = __builtin_amdgcn_readfirstlane(e0);
        const int src = ei[e];
        const int dst = ei[N_EDGES + e];

        const float* td = T + (size_t)dst * 256;
        const float* ts = T + (size_t)src * 256;

        // issue all gathers + the ea row load up front
        float a0  = td[lane];          // Af[dst] (+bf folded)
        float a1  = td[64 + lane];     // As[dst] (+bs folded)
        float b0  = ts[128 + lane];    // Bf[src]
        float b1  = ts[192 + lane];    // Bs[src]
        float eav = ea[(size_t)e * DE + (lane & (DE - 1))];

        float accf = a0 + b0;
        float accs = a1 + b1;

        // broadcast ea[e][c] via v_readlane -> SGPR, feed v_fmac directly
        // (replaces 32x ds_bpermute from __shfl; e is wave-uniform so the
        // broadcast value is genuinely scalar)
#pragma unroll
        for (int c = 0; c < DE; ++c) {
            float z = __int_as_float(
                __builtin_amdgcn_readlane(__float_as_int(eav), c));
            accf = fmaf(z, wfe[c], accf);
            accs = fmaf(z, wse[c], accs);
        }

        // sigmoid(accf) * softplus(accs), numerically stable
        float sig = 1.0f / (1.0f + __expf(-accf));
        float sp  = fmaxf(accs, 0.0f) + log1pf(__expf(-fabsf(accs)));
        atomicAdd(&hout[(size_t)dst * D + lane], sig * sp);
    }
}

// segment_sum(h, batch) into pooled[N_GRAPHS][64]
__global__ __launch_bounds__(256) void pool_kernel(
    const float* __restrict__ h,          // [N_NODES][64]
    const int* __restrict__ batch,        // [N_NODES]
    float* __restrict__ pooled)           // [N_GRAPHS][64], pre-zeroed
{
    const int lane = threadIdx.x & 63;
    const int wid  = threadIdx.x >> 6;
    const int nwaves = gridDim.x * 4;
    for (int n = blockIdx.x * 4 + wid; n < N_NODES; n += nwaves) {
        const int g = batch[n];
        atomicAdd(&pooled[(size_t)g * D + lane], h[(size_t)n * D + lane]);
    }
}

__global__ __launch_bounds__(256) void out_kernel(
    const float* __restrict__ pooled,     // [N_GRAPHS][64]
    const float* __restrict__ Wout,       // [64]
    const float* __restrict__ bout,       // [1]
    float* __restrict__ out)              // [N_GRAPHS]
{
    const int g = blockIdx.x * blockDim.x + threadIdx.x;
    if (g >= N_GRAPHS) return;
    float acc = bout[0];
#pragma unroll
    for (int j = 0; j < D; ++j) acc = fmaf(pooled[(size_t)g * D + j], Wout[j], acc);
    out[g] = acc;
}

extern "C" void kernel_launch(void* const* d_in, const int* in_sizes, int n_in,
                              void* d_out, int out_size, void* d_ws, size_t ws_size,
                              hipStream_t stream) {
    const float* x     = (const float*)d_in[0];
    const int*   ei    = (const int*)  d_in[1];
    const float* ea    = (const float*)d_in[2];
    const int*   batch = (const int*)  d_in[3];
    const float* Wf1   = (const float*)d_in[4];
    const float* bf1   = (const float*)d_in[5];
    const float* Ws1   = (const float*)d_in[6];
    const float* bs1   = (const float*)d_in[7];
    const float* Wf2   = (const float*)d_in[8];
    const float* bf2   = (const float*)d_in[9];
    const float* Ws2   = (const float*)d_in[10];
    const float* bs2   = (const float*)d_in[11];
    const float* Wout  = (const float*)d_in[12];
    const float* bout  = (const float*)d_in[13];
    float* out = (float*)d_out;

    // workspace layout
    float* T      = (float*)d_ws;                       // 50000*256
    float* h1     = T + (size_t)N_NODES * 256;          // 50000*64
    float* h2     = h1 + (size_t)N_NODES * D;           // 50000*64
    float* pooled = h2 + (size_t)N_NODES * D;           // 512*64

    const int GRID_N = 1024;    // node_transform blocks
    const int GRID_E = 25000;   // edge_message blocks (4 waves each, 8 edges/wave)

    // ---- layer 1 ----
    node_transform<<<GRID_N, 256, 0, stream>>>(x, Wf1, Ws1, bf1, bs1, T);
    hipMemcpyAsync(h1, x, (size_t)N_NODES * D * sizeof(float),
                   hipMemcpyDeviceToDevice, stream);
    edge_message<<<GRID_E, 256, 0, stream>>>(T, ei, ea, Wf1, Ws1, h1);

    // ---- layer 2 ----
    node_transform<<<GRID_N, 256, 0, stream>>>(h1, Wf2, Ws2, bf2, bs2, T);
    hipMemcpyAsync(h2, h1, (size_t)N_NODES * D * sizeof(float),
                   hipMemcpyDeviceToDevice, stream);
    edge_message<<<GRID_E, 256, 0, stream>>>(T, ei, ea, Wf2, Ws2, h2);

    // ---- pool + out ----
    hipMemsetAsync(pooled, 0, (size_t)N_GRAPHS * D * sizeof(float), stream);
    pool_kernel<<<12500, 256, 0, stream>>>(h2, batch, pooled);
    out_kernel<<<2, 256, 0, stream>>>(pooled, Wout, bout, out);
}

// Round 4
// 847.272 us; speedup vs baseline: 1.0178x; 1.0102x over previous
//
#include <hip/hip_runtime.h>
#include <math.h>

#define N_NODES 50000
#define N_EDGES 800000
#define N_GRAPHS 512
#define D 64
#define DE 32

// ---------------------------------------------------------------------------
// T table layout per node n (256 floats):
//   T[n*256 +   0 + j] = Af[n][j] = x[n] @ Wf[0:64]  + bf[j]   (dst part, f)
//   T[n*256 +  64 + j] = As[n][j] = x[n] @ Ws[0:64]  + bs[j]   (dst part, s)
//   T[n*256 + 128 + j] = Bf[n][j] = x[n] @ Wf[64:128]          (src part, f)
//   T[n*256 + 192 + j] = Bs[n][j] = x[n] @ Ws[64:128]          (src part, s)
//
// R2 lesson: private float arrays (wcol[64], wfe[32]) were demoted to
// scratch by SROA (dynamic index before unroll) -> ~530 VALU instr/edge.
// All weight state is now named float4 SSA variables, manually unrolled.
// R3 lesson: macro parameter must not be named `w` (collides with .w member).
// ---------------------------------------------------------------------------

// load 4 weight-column entries (row stride 64) into one float4
#define LDW(vec, base, c0)                         \
    vec.x = (base)[((c0) + 0) * 64 + lane];        \
    vec.y = (base)[((c0) + 1) * 64 + lane];        \
    vec.z = (base)[((c0) + 2) * 64 + lane];        \
    vec.w = (base)[((c0) + 3) * 64 + lane];

__global__ __launch_bounds__(256, 4) void node_transform(
    const float* __restrict__ H,          // [N_NODES][64]
    const float* __restrict__ Wf,         // [160][64]
    const float* __restrict__ Ws,         // [160][64]
    const float* __restrict__ bf,         // [64]
    const float* __restrict__ bs,         // [64]
    float* __restrict__ T)                // [N_NODES][256]
{
    const int lane = threadIdx.x & 63;
    const int tbl  = (threadIdx.x >> 6) & 3;  // 0:Af 1:As 2:Bf 3:Bs

    const float* W = (tbl == 0 || tbl == 2) ? Wf : Ws;
    const float* Wb = W + ((tbl < 2) ? 0 : 64 * 64);

    float4 w0, w1, w2, w3, w4, w5, w6, w7, w8, w9, w10, w11, w12, w13, w14, w15;
    LDW(w0,  Wb,  0) LDW(w1,  Wb,  4) LDW(w2,  Wb,  8) LDW(w3,  Wb, 12)
    LDW(w4,  Wb, 16) LDW(w5,  Wb, 20) LDW(w6,  Wb, 24) LDW(w7,  Wb, 28)
    LDW(w8,  Wb, 32) LDW(w9,  Wb, 36) LDW(w10, Wb, 40) LDW(w11, Wb, 44)
    LDW(w12, Wb, 48) LDW(w13, Wb, 52) LDW(w14, Wb, 56) LDW(w15, Wb, 60)

    float bias = 0.0f;
    if (tbl == 0) bias = bf[lane];
    else if (tbl == 1) bias = bs[lane];

#define NT4(i, wv)                                    \
    { float4 v = xr[i];                               \
      acc0 = fmaf(v.x, wv.x, acc0);                   \
      acc1 = fmaf(v.y, wv.y, acc1);                   \
      acc0 = fmaf(v.z, wv.z, acc0);                   \
      acc1 = fmaf(v.w, wv.w, acc1); }

    for (int n = blockIdx.x; n < N_NODES; n += gridDim.x) {
        const float4* xr = (const float4*)(H + (size_t)n * D);
        float acc0 = bias, acc1 = 0.0f;
        NT4(0, w0)   NT4(1, w1)   NT4(2, w2)   NT4(3, w3)
        NT4(4, w4)   NT4(5, w5)   NT4(6, w6)   NT4(7, w7)
        NT4(8, w8)   NT4(9, w9)   NT4(10, w10) NT4(11, w11)
        NT4(12, w12) NT4(13, w13) NT4(14, w14) NT4(15, w15)
        T[(size_t)n * 256 + tbl * 64 + lane] = acc0 + acc1;
    }
#undef NT4
}

// One wave per edge (grid-strided). Lane j computes output channel j.
__global__ __launch_bounds__(256, 4) void edge_message(
    const float* __restrict__ T,          // [N_NODES][256]
    const int* __restrict__ ei,           // [2][N_EDGES]
    const float* __restrict__ ea,         // [N_EDGES][32]
    const float* __restrict__ Wf,         // [160][64] (rows 128..159 used)
    const float* __restrict__ Ws,
    float* __restrict__ hout)             // [N_NODES][64], pre-init to input h
{
    const int lane = threadIdx.x & 63;
    const int wid  = threadIdx.x >> 6;

    // edge-attr weight columns: 16 named float4 = 64 VGPRs, SSA-guaranteed
    const float* Wfe = Wf + 128 * 64;
    const float* Wse = Ws + 128 * 64;
    float4 f0, f1, f2, f3, f4, f5, f6, f7;
    float4 s0, s1, s2, s3, s4, s5, s6, s7;
    LDW(f0, Wfe,  0) LDW(f1, Wfe,  4) LDW(f2, Wfe,  8) LDW(f3, Wfe, 12)
    LDW(f4, Wfe, 16) LDW(f5, Wfe, 20) LDW(f6, Wfe, 24) LDW(f7, Wfe, 28)
    LDW(s0, Wse,  0) LDW(s1, Wse,  4) LDW(s2, Wse,  8) LDW(s3, Wse, 12)
    LDW(s4, Wse, 16) LDW(s5, Wse, 20) LDW(s6, Wse, 24) LDW(s7, Wse, 28)

#define RL(c) __int_as_float(__builtin_amdgcn_readlane(ieav, (c)))
#define EDGE4(c0, vf, vs)                                           \
    { float z0 = RL(c0 + 0), z1 = RL(c0 + 1);                       \
      float z2 = RL(c0 + 2), z3 = RL(c0 + 3);                       \
      accf0 = fmaf(z0, vf.x, accf0); accs0 = fmaf(z0, vs.x, accs0); \
      accf1 = fmaf(z1, vf.y, accf1); accs1 = fmaf(z1, vs.y, accs1); \
      accf0 = fmaf(z2, vf.z, accf0); accs0 = fmaf(z2, vs.z, accs0); \
      accf1 = fmaf(z3, vf.w, accf1); accs1 = fmaf(z3, vs.w, accs1); }

    const int nwaves = gridDim.x * 4;
    for (int e0 = blockIdx.x * 4 + wid; e0 < N_EDGES; e0 += nwaves) {
        const int e   = __builtin_amdgcn_readfirstlane(e0);
        const int src = ei[e];
        const int dst = ei[N_EDGES + e];

        const float* td = T + (size_t)dst * 256;
        const float* ts = T + (size_t)src * 256;

        float a0  = td[lane];          // Af[dst] (+bf folded)
        float a1  = td[64 + lane];     // As[dst] (+bs folded)
        float b0  = ts[128 + lane];    // Bf[src]
        float b1  = ts[192 + lane];    // Bs[src]
        float eav = ea[(size_t)e * DE + (lane & (DE - 1))];
        int  ieav = __float_as_int(eav);

        float accf0 = a0, accf1 = b0;
        float accs0 = a1, accs1 = b1;
        EDGE4(0,  f0, s0) EDGE4(4,  f1, s1) EDGE4(8,  f2, s2) EDGE4(12, f3, s3)
        EDGE4(16, f4, s4) EDGE4(20, f5, s5) EDGE4(24, f6, s6) EDGE4(28, f7, s7)
        float accf = accf0 + accf1;
        float accs = accs0 + accs1;

        // sigmoid(accf) * softplus(accs), numerically stable
        float sig = 1.0f / (1.0f + __expf(-accf));
        float sp  = fmaxf(accs, 0.0f) + log1pf(__expf(-fabsf(accs)));
        atomicAdd(&hout[(size_t)dst * D + lane], sig * sp);
    }
#undef EDGE4
#undef RL
}

// segment_sum(h, batch) into pooled[N_GRAPHS][64]
__global__ __launch_bounds__(256) void pool_kernel(
    const float* __restrict__ h,          // [N_NODES][64]
    const int* __restrict__ batch,        // [N_NODES]
    float* __restrict__ pooled)           // [N_GRAPHS][64], pre-zeroed
{
    const int lane = threadIdx.x & 63;
    const int wid  = threadIdx.x >> 6;
    const int nwaves = gridDim.x * 4;
    for (int n = blockIdx.x * 4 + wid; n < N_NODES; n += nwaves) {
        const int g = batch[n];
        atomicAdd(&pooled[(size_t)g * D + lane], h[(size_t)n * D + lane]);
    }
}

__global__ __launch_bounds__(256) void out_kernel(
    const float* __restrict__ pooled,     // [N_GRAPHS][64]
    const float* __restrict__ Wout,       // [64]
    const float* __restrict__ bout,       // [1]
    float* __restrict__ out)              // [N_GRAPHS]
{
    const int g = blockIdx.x * blockDim.x + threadIdx.x;
    if (g >= N_GRAPHS) return;
    float acc = bout[0];
#pragma unroll
    for (int j = 0; j < D; ++j) acc = fmaf(pooled[(size_t)g * D + j], Wout[j], acc);
    out[g] = acc;
}

extern "C" void kernel_launch(void* const* d_in, const int* in_sizes, int n_in,
                              void* d_out, int out_size, void* d_ws, size_t ws_size,
                              hipStream_t stream) {
    const float* x     = (const float*)d_in[0];
    const int*   ei    = (const int*)  d_in[1];
    const float* ea    = (const float*)d_in[2];
    const int*   batch = (const int*)  d_in[3];
    const float* Wf1   = (const float*)d_in[4];
    const float* bf1   = (const float*)d_in[5];
    const float* Ws1   = (const float*)d_in[6];
    const float* bs1   = (const float*)d_in[7];
    const float* Wf2   = (const float*)d_in[8];
    const float* bf2   = (const float*)d_in[9];
    const float* Ws2   = (const float*)d_in[10];
    const float* bs2   = (const float*)d_in[11];
    const float* Wout  = (const float*)d_in[12];
    const float* bout  = (const float*)d_in[13];
    float* out = (float*)d_out;

    // workspace layout
    float* T      = (float*)d_ws;                       // 50000*256
    float* h1     = T + (size_t)N_NODES * 256;          // 50000*64
    float* h2     = h1 + (size_t)N_NODES * D;           // 50000*64
    float* pooled = h2 + (size_t)N_NODES * D;           // 512*64

    const int GRID_N = 1024;    // node_transform blocks
    const int GRID_E = 25000;   // edge_message blocks (4 waves each, 8 edges/wave)

    // ---- layer 1 ----
    node_transform<<<GRID_N, 256, 0, stream>>>(x, Wf1, Ws1, bf1, bs1, T);
    hipMemcpyAsync(h1, x, (size_t)N_NODES * D * sizeof(float),
                   hipMemcpyDeviceToDevice, stream);
    edge_message<<<GRID_E, 256, 0, stream>>>(T, ei, ea, Wf1, Ws1, h1);

    // ---- layer 2 ----
    node_transform<<<GRID_N, 256, 0, stream>>>(h1, Wf2, Ws2, bf2, bs2, T);
    hipMemcpyAsync(h2, h1, (size_t)N_NODES * D * sizeof(float),
                   hipMemcpyDeviceToDevice, stream);
    edge_message<<<GRID_E, 256, 0, stream>>>(T, ei, ea, Wf2, Ws2, h2);

    // ---- pool + out ----
    hipMemsetAsync(pooled, 0, (size_t)N_GRAPHS * D * sizeof(float), stream);
    pool_kernel<<<12500, 256, 0, stream>>>(h2, batch, pooled);
    out_kernel<<<2, 256, 0, stream>>>(pooled, Wout, bout, out);
}